// Round 18
// baseline (1014.205 us; speedup 1.0000x reference)
//
#include <hip/hip_runtime.h>

// ---------------------------------------------------------------------------
// Child-Sum TreeLSTM, complete binary tree, level-wise bottom-up, bf16 MFMA.
// Round 18 = R13 body (byte-identical math; VGPR 60, no spill) + occupancy:
//  - leaf: grid 1024 (lns=6) -> 4 blocks/CU x 8 waves = 32 waves/CU
//    (24KB LDS, 60 regs <= 64; R13 leaf was grid-limited at 2 blocks/CU)
//  - interior: only 6 weight planes in LDS (Wx_i/o/u, Wh_i/o/u = 48KB);
//    Wfx/Wfh B-frags read from GLOBAL per tile (same addr across waves of a
//    cg -> L2 broadcast, ~30us aggregate) -> 3 blocks/CU = 24 waves/CU.
//  - small-level grid sizing: lns = clamp(log2(T16)-3, 0, 6) so tiny levels
//    don't launch 1024 weight-staging blocks.
// R15/R16/R17 lessons kept: no 8-wave reg regime, no big staging arrays,
// no 2-subtile 12-plane body. Tripwires (lvl 16): FETCH ~0.9e5, WRITE ~1.5e5.
//
// mfma_f32_16x16x32_bf16: A lane: row=l&15, k=(l>>4)*8+e  (16B/lane)
//                         B lane: col=l&15, k=(l>>4)*8+e = W[col][k]
//                         D: col=l&15, row=(l>>4)*4+r, r=0..3
// ---------------------------------------------------------------------------

typedef __attribute__((ext_vector_type(8))) short bf16x8;
typedef __attribute__((ext_vector_type(8))) unsigned short us8;
typedef __attribute__((ext_vector_type(4))) float f32x4;
typedef __attribute__((ext_vector_type(4))) float f4;

#define MFMA16(A, B, C) __builtin_amdgcn_mfma_f32_16x16x32_bf16(A, B, C, 0, 0, 0)

__device__ __forceinline__ unsigned short f2b(float f) {
  unsigned int u = __builtin_bit_cast(unsigned int, f);
  u = u + 0x7FFFu + ((u >> 16) & 1u);   // RNE
  return (unsigned short)(u >> 16);
}
__device__ __forceinline__ float bf2f(unsigned short u) {
  unsigned int v = (unsigned int)u << 16;
  return __builtin_bit_cast(float, v);
}
__device__ __forceinline__ us8 pack8(f4 a, f4 b) {
  us8 r;
  r[0] = f2b(a[0]); r[1] = f2b(a[1]); r[2] = f2b(a[2]); r[3] = f2b(a[3]);
  r[4] = f2b(b[0]); r[5] = f2b(b[1]); r[6] = f2b(b[2]); r[7] = f2b(b[3]);
  return r;
}
__device__ __forceinline__ float sigm(float x) { return 1.0f / (1.0f + __expf(-x)); }
__device__ __forceinline__ float tanh_f(float x) { return 2.0f / (1.0f + __expf(-2.0f * x)) - 1.0f; }

__global__ void pack_w(const float* __restrict__ a,  // Wioux 768x256
                       const float* __restrict__ b,  // Wiouh 768x256
                       const float* __restrict__ c,  // Wfx   256x256
                       const float* __restrict__ d,  // Wfh   256x256
                       unsigned short* __restrict__ out) {
  int i = blockIdx.x * blockDim.x + threadIdx.x;  // 0 .. 524287
  const int A = 768 * 256;
  const int B = A + 768 * 256;
  const int C = B + 256 * 256;
  float v;
  if (i < A)      v = a[i];
  else if (i < B) v = b[i - A];
  else if (i < C) v = c[i - B];
  else            v = d[i - C];
  out[i] = f2b(v);
}

// convert ALL node x rows to bf16 (8 elems/thread)
__global__ void conv_x(const float* __restrict__ x, unsigned short* __restrict__ xb, int n8) {
  int i = blockIdx.x * blockDim.x + threadIdx.x;
  if (i >= n8) return;
  f4 a = __builtin_nontemporal_load((const f4*)(x + (size_t)i * 8));
  f4 b = __builtin_nontemporal_load((const f4*)(x + (size_t)i * 8 + 4));
  __builtin_nontemporal_store(pack8(a, b), (us8*)(xb + (size_t)i * 8));
}

// LDS planes: 0 Wx_i, 1 Wx_o, 2 Wx_u, 3 Wh_i, 4 Wh_o, 5 Wh_u  (48KB interior)
// Wfx (wb+393216) / Wfh (wb+458752) stay in global -> L2-broadcast reads.
// per plane: [kc8][kg4][col16][e8] -> a wave's b128 read is 1KB contiguous.
template<int LEAF>
__global__ __launch_bounds__(512) __attribute__((amdgpu_waves_per_eu(3, 4)))
void level_k(
    const unsigned short* __restrict__ xb,     // [N][256] bf16
    const unsigned short* __restrict__ wb,     // packed bf16 weights
    const float* __restrict__ bioux,
    const float* __restrict__ bfx,
    const float* __restrict__ fb,
    float* __restrict__ h_all,                 // d_out + 512
    const unsigned short* __restrict__ hs_r,   // hsum of children, level-local
    const unsigned short* __restrict__ hbe_r,  // h of even child
    const unsigned int* __restrict__ cp_r,     // packed (c_even | c_odd<<16)
    unsigned short* __restrict__ hs_w,         // for parent level
    unsigned short* __restrict__ hbe_w,
    unsigned int* __restrict__ cp_w,
    float* __restrict__ out0,
    int s, int L, int T16, int root, int lns)  // lns: log2(stripe count)
{
  extern __shared__ unsigned short W[];

  const int tid    = threadIdx.x;
  const int NS     = 1 << lns;
  const int cg     = blockIdx.x >> lns;       // column group (16 cols)
  const int stripe = blockIdx.x & (NS - 1);

  // ---- stage weights for this cg into LDS (once) ----
  const int NP = LEAF ? 3 : 6;
  #pragma unroll 1
  for (int c = tid; c < NP * 512; c += 512) {
    const int p   = c >> 9;
    const int q   = c & 511;
    const int kc  = q >> 6;
    const int kg  = (q >> 4) & 3;
    const int col = q & 15;
    const int po = (p < 3) ? p * 65536 : 196608 + (p - 3) * 65536;
    us8 v = *(const us8*)(wb + po + (size_t)(cg * 16 + col) * 256 + kc * 32 + kg * 8);
    *(us8*)(W + p * 4096 + ((kc * 4 + kg) * 16 + col) * 8) = v;
  }
  __syncthreads();   // only barrier; waves free-run after

  const int lane = tid & 63;
  const int wv   = tid >> 6;          // 0..7
  const int lm   = lane & 15;
  const int kgl  = lane >> 4;         // 0..3
  const int colc = cg * 16 + lm;

  const unsigned short* LW = W + kgl * 128 + lm * 8;  // + p*4096 + kc*512
  // global B-frag bases for Wfx / Wfh (interior only)
  const unsigned short* wfxg = wb + 393216 + (size_t)colc * 256 + kgl * 8;
  const unsigned short* wfhg = wb + 458752 + (size_t)colc * 256 + kgl * 8;

  const float bi_ = bioux[colc];
  const float bo_ = bioux[256 + colc];
  const float bu_ = bioux[512 + colc];
  const float bf_ = LEAF ? 0.f : (bfx[colc] + fb[colc]);

  const int Tper = (T16 + NS - 1) >> lns;
  const int t0   = stripe * Tper;
  const int tE   = (t0 + Tper < T16) ? (t0 + Tper) : T16;

  for (int t = t0 + wv; t < tE; t += 8) {
    const int tb16  = t * 16;
    const int drow0 = tb16 + kgl * 4;
    const unsigned short* xr = xb + (size_t)(s + tb16 + lm) * 256 + kgl * 8;
    const f32x4 z4 = {0.f, 0.f, 0.f, 0.f};

    if (!LEAF) {
      const unsigned short* hbr = hbe_r + (size_t)(tb16 + lm) * 256 + kgl * 8;
      const unsigned short* hsr = hs_r  + (size_t)(tb16 + lm) * 256 + kgl * 8;

      unsigned int cpv[4];
      #pragma unroll
      for (int r = 0; r < 4; ++r)
        cpv[r] = cp_r[(size_t)(drow0 + r) * 256 + colc];

      // ---- merged K-sweep: all 6 acc planes, each A-frag loaded once ----
      f32x4 xf = z4, f1h = z4, ai = z4, ao = z4, au = z4, fs = z4;
      #pragma unroll 2
      for (int kc = 0; kc < 8; ++kc) {
        bf16x8 ax = *(const bf16x8*)(xr  + kc * 32);
        bf16x8 a1 = *(const bf16x8*)(hbr + kc * 32);
        bf16x8 ah = *(const bf16x8*)(hsr + kc * 32);
        bf16x8 b6 = *(const bf16x8*)(wfxg + kc * 32);   // global, L2-broadcast
        bf16x8 b7 = *(const bf16x8*)(wfhg + kc * 32);   // global, L2-broadcast
        bf16x8 b0 = *(const bf16x8*)(LW + 0 * 4096 + kc * 512);
        bf16x8 b1 = *(const bf16x8*)(LW + 1 * 4096 + kc * 512);
        bf16x8 b2 = *(const bf16x8*)(LW + 2 * 4096 + kc * 512);
        bf16x8 b3 = *(const bf16x8*)(LW + 3 * 4096 + kc * 512);
        bf16x8 b4 = *(const bf16x8*)(LW + 4 * 4096 + kc * 512);
        bf16x8 b5 = *(const bf16x8*)(LW + 5 * 4096 + kc * 512);
        xf  = MFMA16(ax, b6, xf);
        ai  = MFMA16(ax, b0, ai);
        ao  = MFMA16(ax, b1, ao);
        au  = MFMA16(ax, b2, au);
        f1h = MFMA16(a1, b7, f1h);
        ai  = MFMA16(ah, b3, ai);
        ao  = MFMA16(ah, b4, ao);
        au  = MFMA16(ah, b5, au);
        fs  = MFMA16(ah, b7, fs);
      }

      // ---- epilogue ----
      float hv4[4], cv4[4];
      #pragma unroll
      for (int r = 0; r < 4; ++r) {
        const float i_ = sigm(ai[r] + bi_);
        const float u_ = tanh_f(au[r] + bu_);
        const float o_ = sigm(ao[r] + bo_);
        const float f1 = sigm(xf[r] + f1h[r] + bf_);
        const float f2 = sigm(xf[r] + fs[r] - f1h[r] + bf_);  // h2@W = hs@W - h1@W
        const float c1 = bf2f((unsigned short)(cpv[r] & 0xffffu));
        const float c2 = bf2f((unsigned short)(cpv[r] >> 16));
        const float c_ = i_ * u_ + f1 * c1 + f2 * c2;
        const float h_ = o_ * tanh_f(c_);
        cv4[r] = c_; hv4[r] = h_;
        const int j = drow0 + r;
        if (j < L)
          __builtin_nontemporal_store(h_, h_all + (size_t)(s + j) * 256 + colc);
      }
      if (root) {
        if (drow0 == 0) { out0[colc] = hv4[0]; out0[256 + colc] = cv4[0]; }
      } else {
        #pragma unroll
        for (int rp = 0; rp < 2; ++rp) {
          const int j0 = drow0 + rp * 2;
          if (j0 + 1 < L) {
            const int pp = j0 >> 1;
            hs_w [(size_t)pp * 256 + colc] = f2b(hv4[rp*2] + hv4[rp*2+1]);
            hbe_w[(size_t)pp * 256 + colc] = f2b(hv4[rp*2]);
            cp_w [(size_t)pp * 256 + colc] =
                (unsigned int)f2b(cv4[rp*2]) | ((unsigned int)f2b(cv4[rp*2+1]) << 16);
          }
        }
      }
    } else {
      // ---- leaf: i,o,u from x only ----
      f32x4 ai = z4, ao = z4, au = z4;
      #pragma unroll 4
      for (int kc = 0; kc < 8; ++kc) {
        bf16x8 ax = *(const bf16x8*)(xr + kc * 32);
        bf16x8 b0 = *(const bf16x8*)(LW + 0 * 4096 + kc * 512);
        bf16x8 b1 = *(const bf16x8*)(LW + 1 * 4096 + kc * 512);
        bf16x8 b2 = *(const bf16x8*)(LW + 2 * 4096 + kc * 512);
        ai = MFMA16(ax, b0, ai);
        ao = MFMA16(ax, b1, ao);
        au = MFMA16(ax, b2, au);
      }
      float hv4[4], cv4[4];
      #pragma unroll
      for (int r = 0; r < 4; ++r) {
        const float i_ = sigm(ai[r] + bi_);
        const float u_ = tanh_f(au[r] + bu_);
        const float o_ = sigm(ao[r] + bo_);
        const float c_ = i_ * u_;
        const float h_ = o_ * tanh_f(c_);
        cv4[r] = c_; hv4[r] = h_;
        __builtin_nontemporal_store(h_, h_all + (size_t)(s + drow0 + r) * 256 + colc);
      }
      #pragma unroll
      for (int rp = 0; rp < 2; ++rp) {
        const int pp = (drow0 + rp * 2) >> 1;
        hs_w [(size_t)pp * 256 + colc] = f2b(hv4[rp*2] + hv4[rp*2+1]);
        hbe_w[(size_t)pp * 256 + colc] = f2b(hv4[rp*2]);
        cp_w [(size_t)pp * 256 + colc] =
            (unsigned int)f2b(cv4[rp*2]) | ((unsigned int)f2b(cv4[rp*2+1]) << 16);
      }
    }
  }
}

extern "C" void kernel_launch(void* const* d_in, const int* in_sizes, int n_in,
                              void* d_out, int out_size, void* d_ws, size_t ws_size,
                              hipStream_t stream) {
  const float* inputs = (const float*)d_in[0];
  const float* Wioux  = (const float*)d_in[1];
  const float* bioux  = (const float*)d_in[2];
  const float* Wiouh  = (const float*)d_in[3];
  const float* Wfx    = (const float*)d_in[4];
  const float* bfx    = (const float*)d_in[5];
  const float* Wfh    = (const float*)d_in[6];
  const float* fb     = (const float*)d_in[7];

  const int N = in_sizes[0] / 256;       // 262143
  int depth = 0;
  while (((1 << depth) - 1) < N) ++depth;  // 18

  float* out   = (float*)d_out;
  float* h_all = out + 512;

  static bool attr_done = false;
  if (!attr_done) {
    hipFuncSetAttribute((const void*)level_k<0>,
                        hipFuncAttributeMaxDynamicSharedMemorySize, 6 * 8192);
    hipFuncSetAttribute((const void*)level_k<1>,
                        hipFuncAttributeMaxDynamicSharedMemorySize, 3 * 8192);
    attr_done = true;
  }

  // ws carve: parity-0 buffers (up to 65536 rows), parity-1 (32768), xb, wb
  char* p = (char*)d_ws;
  unsigned short* hs0  = (unsigned short*)p; p += (size_t)65536 * 256 * 2;
  unsigned short* hbe0 = (unsigned short*)p; p += (size_t)65536 * 256 * 2;
  unsigned int*   cp0  = (unsigned int*)p;   p += (size_t)65536 * 256 * 4;
  unsigned short* hs1  = (unsigned short*)p; p += (size_t)32768 * 256 * 2;
  unsigned short* hbe1 = (unsigned short*)p; p += (size_t)32768 * 256 * 2;
  unsigned int*   cp1  = (unsigned int*)p;   p += (size_t)32768 * 256 * 4;
  unsigned short* xb   = (unsigned short*)p; p += (size_t)N * 256 * 2;
  unsigned short* wb   = (unsigned short*)p;

  pack_w<<<2048, 256, 0, stream>>>(Wioux, Wiouh, Wfx, Wfh, wb);
  {
    const int n8 = (N * 256) / 8;
    conv_x<<<(n8 + 255) / 256, 256, 0, stream>>>(inputs, xb, n8);
  }

  for (int d = depth - 1; d >= 0; --d) {
    const int L = 1 << d;
    const int s = L - 1;
    const int T16 = (L + 15) / 16;
    // stripes: aim Tper ~ 8-16, cap NS=64
    int lg = 0; while ((1 << (lg + 1)) <= T16) ++lg;   // floor(log2 T16)
    int lns = lg - 3; if (lns < 0) lns = 0; if (lns > 6) lns = 6;
    const int rp_ = d & 1, wp_ = (d - 1) & 1;
    const unsigned short* hs_r  = rp_ ? hs1 : hs0;
    const unsigned short* hbe_r = rp_ ? hbe1 : hbe0;
    const unsigned int*   cp_r  = rp_ ? cp1 : cp0;
    unsigned short* hs_w  = wp_ ? hs1 : hs0;
    unsigned short* hbe_w = wp_ ? hbe1 : hbe0;
    unsigned int*   cp_w  = wp_ ? cp1 : cp0;
    if (d == depth - 1) {
      // leaf: 24KB LDS -> 4 blocks/CU; grid 1024 (lns=6) -> 32 waves/CU
      level_k<1><<<16 * 64, 512, 3 * 8192, stream>>>(
          xb, wb, bioux, bfx, fb, h_all,
          hs_r, hbe_r, cp_r, hs_w, hbe_w, cp_w, out, s, L, T16, 0, 6);
    } else {
      // interior: 48KB LDS -> 3 blocks/CU; grid = 16 << lns (up to 1024)
      level_k<0><<<16 << lns, 512, 6 * 8192, stream>>>(
          xb, wb, bioux, bfx, fb, h_all,
          hs_r, hbe_r, cp_r, hs_w, hbe_w, cp_w, out, s, L, T16, (d == 0) ? 1 : 0, lns);
    }
  }
}

// Round 19
// 803.828 us; speedup vs baseline: 1.2617x; 1.2617x over previous
//
#include <hip/hip_runtime.h>

// ---------------------------------------------------------------------------
// Child-Sum TreeLSTM, complete binary tree, level-wise bottom-up, bf16 MFMA.
// Round 19 = R13 EXACT body (VGPR 60, no spill, 229us/lvl16) + launch-only:
//  - leaf grid 1024 (lns=6): 24KB LDS, VGPR60<=64 -> 4 blocks/CU x 8 waves
//    = 32 waves/CU (R13 leaf was grid-limited to 2 blocks/CU)
//  - small levels: lns = clamp(log2(T16)-3, 0, 5) -> grid 16<<lns, so tiny
//    levels stop paying 512 x 64KB weight staging
//  - interior big levels: identical to R13 (grid 512, 8 planes in LDS)
// R14-R18 lessons: no reg-array staging, no 8-wave reg regime, no global
// B-reads, no 12-plane body. Tripwires (lvl16): FETCH ~8.6e4, WRITE ~1.5e5,
// VGPR 60 — must match R13 exactly.
//
// mfma_f32_16x16x32_bf16: A lane: row=l&15, k=(l>>4)*8+e  (16B/lane)
//                         B lane: col=l&15, k=(l>>4)*8+e = W[col][k]
//                         D: col=l&15, row=(l>>4)*4+r, r=0..3
// ---------------------------------------------------------------------------

typedef __attribute__((ext_vector_type(8))) short bf16x8;
typedef __attribute__((ext_vector_type(8))) unsigned short us8;
typedef __attribute__((ext_vector_type(4))) float f32x4;
typedef __attribute__((ext_vector_type(4))) float f4;

#define MFMA16(A, B, C) __builtin_amdgcn_mfma_f32_16x16x32_bf16(A, B, C, 0, 0, 0)

__device__ __forceinline__ unsigned short f2b(float f) {
  unsigned int u = __builtin_bit_cast(unsigned int, f);
  u = u + 0x7FFFu + ((u >> 16) & 1u);   // RNE
  return (unsigned short)(u >> 16);
}
__device__ __forceinline__ float bf2f(unsigned short u) {
  unsigned int v = (unsigned int)u << 16;
  return __builtin_bit_cast(float, v);
}
__device__ __forceinline__ us8 pack8(f4 a, f4 b) {
  us8 r;
  r[0] = f2b(a[0]); r[1] = f2b(a[1]); r[2] = f2b(a[2]); r[3] = f2b(a[3]);
  r[4] = f2b(b[0]); r[5] = f2b(b[1]); r[6] = f2b(b[2]); r[7] = f2b(b[3]);
  return r;
}
__device__ __forceinline__ float sigm(float x) { return 1.0f / (1.0f + __expf(-x)); }
__device__ __forceinline__ float tanh_f(float x) { return 2.0f / (1.0f + __expf(-2.0f * x)) - 1.0f; }

__global__ void pack_w(const float* __restrict__ a,  // Wioux 768x256
                       const float* __restrict__ b,  // Wiouh 768x256
                       const float* __restrict__ c,  // Wfx   256x256
                       const float* __restrict__ d,  // Wfh   256x256
                       unsigned short* __restrict__ out) {
  int i = blockIdx.x * blockDim.x + threadIdx.x;  // 0 .. 524287
  const int A = 768 * 256;
  const int B = A + 768 * 256;
  const int C = B + 256 * 256;
  float v;
  if (i < A)      v = a[i];
  else if (i < B) v = b[i - A];
  else if (i < C) v = c[i - B];
  else            v = d[i - C];
  out[i] = f2b(v);
}

// convert ALL node x rows to bf16 (8 elems/thread)
__global__ void conv_x(const float* __restrict__ x, unsigned short* __restrict__ xb, int n8) {
  int i = blockIdx.x * blockDim.x + threadIdx.x;
  if (i >= n8) return;
  f4 a = __builtin_nontemporal_load((const f4*)(x + (size_t)i * 8));
  f4 b = __builtin_nontemporal_load((const f4*)(x + (size_t)i * 8 + 4));
  __builtin_nontemporal_store(pack8(a, b), (us8*)(xb + (size_t)i * 8));
}

// LDS planes: 0 Wx_i, 1 Wx_o, 2 Wx_u, 3 Wh_i, 4 Wh_o, 5 Wh_u, 6 Wfx, 7 Wfh
// per plane: [kc8][kg4][col16][e8] -> a wave's b128 read is 1KB contiguous.
template<int LEAF>
__global__ __launch_bounds__(512) __attribute__((amdgpu_waves_per_eu(3, 4)))
void level_k(
    const unsigned short* __restrict__ xb,     // [N][256] bf16
    const unsigned short* __restrict__ wb,     // packed bf16 weights
    const float* __restrict__ bioux,
    const float* __restrict__ bfx,
    const float* __restrict__ fb,
    float* __restrict__ h_all,                 // d_out + 512
    const unsigned short* __restrict__ hs_r,   // hsum of children, level-local
    const unsigned short* __restrict__ hbe_r,  // h of even child
    const unsigned int* __restrict__ cp_r,     // packed (c_even | c_odd<<16)
    unsigned short* __restrict__ hs_w,         // for parent level
    unsigned short* __restrict__ hbe_w,
    unsigned int* __restrict__ cp_w,
    float* __restrict__ out0,
    int s, int L, int T16, int root, int lns)  // lns: log2(stripe count)
{
  extern __shared__ unsigned short W[];

  const int tid    = threadIdx.x;
  const int NS     = 1 << lns;
  const int cg     = blockIdx.x >> lns;       // column group (16 cols)
  const int stripe = blockIdx.x & (NS - 1);

  // ---- stage weights for this cg into LDS (once) ----
  const int NP = LEAF ? 3 : 8;
  #pragma unroll 1
  for (int c = tid; c < NP * 512; c += 512) {
    const int p   = c >> 9;
    const int q   = c & 511;
    const int kc  = q >> 6;
    const int kg  = (q >> 4) & 3;
    const int col = q & 15;
    const int po = (p < 3) ? p * 65536
                 : (p < 6) ? 196608 + (p - 3) * 65536
                 : (p == 6) ? 393216 : 458752;
    us8 v = *(const us8*)(wb + po + (size_t)(cg * 16 + col) * 256 + kc * 32 + kg * 8);
    *(us8*)(W + p * 4096 + ((kc * 4 + kg) * 16 + col) * 8) = v;
  }
  __syncthreads();   // only barrier; waves free-run after

  const int lane = tid & 63;
  const int wv   = tid >> 6;          // 0..7
  const int lm   = lane & 15;
  const int kgl  = lane >> 4;         // 0..3
  const int colc = cg * 16 + lm;

  const unsigned short* LW = W + kgl * 128 + lm * 8;  // + p*4096 + kc*512

  const float bi_ = bioux[colc];
  const float bo_ = bioux[256 + colc];
  const float bu_ = bioux[512 + colc];
  const float bf_ = LEAF ? 0.f : (bfx[colc] + fb[colc]);

  const int Tper = (T16 + NS - 1) >> lns;
  const int t0   = stripe * Tper;
  const int tE   = (t0 + Tper < T16) ? (t0 + Tper) : T16;

  for (int t = t0 + wv; t < tE; t += 8) {
    const int tb16  = t * 16;
    const int drow0 = tb16 + kgl * 4;
    const unsigned short* xr = xb + (size_t)(s + tb16 + lm) * 256 + kgl * 8;
    const f32x4 z4 = {0.f, 0.f, 0.f, 0.f};

    if (!LEAF) {
      const unsigned short* hbr = hbe_r + (size_t)(tb16 + lm) * 256 + kgl * 8;
      const unsigned short* hsr = hs_r  + (size_t)(tb16 + lm) * 256 + kgl * 8;

      unsigned int cpv[4];
      #pragma unroll
      for (int r = 0; r < 4; ++r)
        cpv[r] = cp_r[(size_t)(drow0 + r) * 256 + colc];

      // ---- merged K-sweep: all 6 acc planes, each A-frag loaded once ----
      f32x4 xf = z4, f1h = z4, ai = z4, ao = z4, au = z4, fs = z4;
      #pragma unroll 2
      for (int kc = 0; kc < 8; ++kc) {
        bf16x8 ax = *(const bf16x8*)(xr  + kc * 32);
        bf16x8 a1 = *(const bf16x8*)(hbr + kc * 32);
        bf16x8 ah = *(const bf16x8*)(hsr + kc * 32);
        bf16x8 b6 = *(const bf16x8*)(LW + 6 * 4096 + kc * 512);
        bf16x8 b0 = *(const bf16x8*)(LW + 0 * 4096 + kc * 512);
        bf16x8 b1 = *(const bf16x8*)(LW + 1 * 4096 + kc * 512);
        bf16x8 b2 = *(const bf16x8*)(LW + 2 * 4096 + kc * 512);
        bf16x8 b7 = *(const bf16x8*)(LW + 7 * 4096 + kc * 512);
        bf16x8 b3 = *(const bf16x8*)(LW + 3 * 4096 + kc * 512);
        bf16x8 b4 = *(const bf16x8*)(LW + 4 * 4096 + kc * 512);
        bf16x8 b5 = *(const bf16x8*)(LW + 5 * 4096 + kc * 512);
        xf  = MFMA16(ax, b6, xf);
        ai  = MFMA16(ax, b0, ai);
        ao  = MFMA16(ax, b1, ao);
        au  = MFMA16(ax, b2, au);
        f1h = MFMA16(a1, b7, f1h);
        ai  = MFMA16(ah, b3, ai);
        ao  = MFMA16(ah, b4, ao);
        au  = MFMA16(ah, b5, au);
        fs  = MFMA16(ah, b7, fs);
      }

      // ---- epilogue ----
      float hv4[4], cv4[4];
      #pragma unroll
      for (int r = 0; r < 4; ++r) {
        const float i_ = sigm(ai[r] + bi_);
        const float u_ = tanh_f(au[r] + bu_);
        const float o_ = sigm(ao[r] + bo_);
        const float f1 = sigm(xf[r] + f1h[r] + bf_);
        const float f2 = sigm(xf[r] + fs[r] - f1h[r] + bf_);  // h2@W = hs@W - h1@W
        const float c1 = bf2f((unsigned short)(cpv[r] & 0xffffu));
        const float c2 = bf2f((unsigned short)(cpv[r] >> 16));
        const float c_ = i_ * u_ + f1 * c1 + f2 * c2;
        const float h_ = o_ * tanh_f(c_);
        cv4[r] = c_; hv4[r] = h_;
        const int j = drow0 + r;
        if (j < L)
          __builtin_nontemporal_store(h_, h_all + (size_t)(s + j) * 256 + colc);
      }
      if (root) {
        if (drow0 == 0) { out0[colc] = hv4[0]; out0[256 + colc] = cv4[0]; }
      } else {
        #pragma unroll
        for (int rp = 0; rp < 2; ++rp) {
          const int j0 = drow0 + rp * 2;
          if (j0 + 1 < L) {
            const int pp = j0 >> 1;
            hs_w [(size_t)pp * 256 + colc] = f2b(hv4[rp*2] + hv4[rp*2+1]);
            hbe_w[(size_t)pp * 256 + colc] = f2b(hv4[rp*2]);
            cp_w [(size_t)pp * 256 + colc] =
                (unsigned int)f2b(cv4[rp*2]) | ((unsigned int)f2b(cv4[rp*2+1]) << 16);
          }
        }
      }
    } else {
      // ---- leaf: i,o,u from x only ----
      f32x4 ai = z4, ao = z4, au = z4;
      #pragma unroll 4
      for (int kc = 0; kc < 8; ++kc) {
        bf16x8 ax = *(const bf16x8*)(xr + kc * 32);
        bf16x8 b0 = *(const bf16x8*)(LW + 0 * 4096 + kc * 512);
        bf16x8 b1 = *(const bf16x8*)(LW + 1 * 4096 + kc * 512);
        bf16x8 b2 = *(const bf16x8*)(LW + 2 * 4096 + kc * 512);
        ai = MFMA16(ax, b0, ai);
        ao = MFMA16(ax, b1, ao);
        au = MFMA16(ax, b2, au);
      }
      float hv4[4], cv4[4];
      #pragma unroll
      for (int r = 0; r < 4; ++r) {
        const float i_ = sigm(ai[r] + bi_);
        const float u_ = tanh_f(au[r] + bu_);
        const float o_ = sigm(ao[r] + bo_);
        const float c_ = i_ * u_;
        const float h_ = o_ * tanh_f(c_);
        cv4[r] = c_; hv4[r] = h_;
        __builtin_nontemporal_store(h_, h_all + (size_t)(s + drow0 + r) * 256 + colc);
      }
      #pragma unroll
      for (int rp = 0; rp < 2; ++rp) {
        const int pp = (drow0 + rp * 2) >> 1;
        hs_w [(size_t)pp * 256 + colc] = f2b(hv4[rp*2] + hv4[rp*2+1]);
        hbe_w[(size_t)pp * 256 + colc] = f2b(hv4[rp*2]);
        cp_w [(size_t)pp * 256 + colc] =
            (unsigned int)f2b(cv4[rp*2]) | ((unsigned int)f2b(cv4[rp*2+1]) << 16);
      }
    }
  }
}

extern "C" void kernel_launch(void* const* d_in, const int* in_sizes, int n_in,
                              void* d_out, int out_size, void* d_ws, size_t ws_size,
                              hipStream_t stream) {
  const float* inputs = (const float*)d_in[0];
  const float* Wioux  = (const float*)d_in[1];
  const float* bioux  = (const float*)d_in[2];
  const float* Wiouh  = (const float*)d_in[3];
  const float* Wfx    = (const float*)d_in[4];
  const float* bfx    = (const float*)d_in[5];
  const float* Wfh    = (const float*)d_in[6];
  const float* fb     = (const float*)d_in[7];

  const int N = in_sizes[0] / 256;       // 262143
  int depth = 0;
  while (((1 << depth) - 1) < N) ++depth;  // 18

  float* out   = (float*)d_out;
  float* h_all = out + 512;

  static bool attr_done = false;
  if (!attr_done) {
    hipFuncSetAttribute((const void*)level_k<0>,
                        hipFuncAttributeMaxDynamicSharedMemorySize, 8 * 8192);
    hipFuncSetAttribute((const void*)level_k<1>,
                        hipFuncAttributeMaxDynamicSharedMemorySize, 3 * 8192);
    attr_done = true;
  }

  // ws carve: parity-0 buffers (up to 65536 rows), parity-1 (32768), xb, wb
  char* p = (char*)d_ws;
  unsigned short* hs0  = (unsigned short*)p; p += (size_t)65536 * 256 * 2;
  unsigned short* hbe0 = (unsigned short*)p; p += (size_t)65536 * 256 * 2;
  unsigned int*   cp0  = (unsigned int*)p;   p += (size_t)65536 * 256 * 4;
  unsigned short* hs1  = (unsigned short*)p; p += (size_t)32768 * 256 * 2;
  unsigned short* hbe1 = (unsigned short*)p; p += (size_t)32768 * 256 * 2;
  unsigned int*   cp1  = (unsigned int*)p;   p += (size_t)32768 * 256 * 4;
  unsigned short* xb   = (unsigned short*)p; p += (size_t)N * 256 * 2;
  unsigned short* wb   = (unsigned short*)p;

  pack_w<<<2048, 256, 0, stream>>>(Wioux, Wiouh, Wfx, Wfh, wb);
  {
    const int n8 = (N * 256) / 8;
    conv_x<<<(n8 + 255) / 256, 256, 0, stream>>>(inputs, xb, n8);
  }

  for (int d = depth - 1; d >= 0; --d) {
    const int L = 1 << d;
    const int s = L - 1;
    const int T16 = (L + 15) / 16;
    // interior stripes: aim Tper ~ 8-16, cap NS=32 (matches R13 at big levels)
    int lg = 0; while ((1 << (lg + 1)) <= T16) ++lg;   // floor(log2 T16)
    int lns = lg - 3; if (lns < 0) lns = 0; if (lns > 5) lns = 5;
    const int rp_ = d & 1, wp_ = (d - 1) & 1;
    const unsigned short* hs_r  = rp_ ? hs1 : hs0;
    const unsigned short* hbe_r = rp_ ? hbe1 : hbe0;
    const unsigned int*   cp_r  = rp_ ? cp1 : cp0;
    unsigned short* hs_w  = wp_ ? hs1 : hs0;
    unsigned short* hbe_w = wp_ ? hbe1 : hbe0;
    unsigned int*   cp_w  = wp_ ? cp1 : cp0;
    if (d == depth - 1) {
      // leaf: 24KB LDS + VGPR60 -> 4 blocks/CU; grid 1024 (lns=6) = 32 waves/CU
      level_k<1><<<16 * 64, 512, 3 * 8192, stream>>>(
          xb, wb, bioux, bfx, fb, h_all,
          hs_r, hbe_r, cp_r, hs_w, hbe_w, cp_w, out, s, L, T16, 0, 6);
    } else {
      // interior: 64KB LDS -> 2 blocks/CU; grid = 16 << lns (512 at big levels)
      level_k<0><<<16 << lns, 512, 8 * 8192, stream>>>(
          xb, wb, bioux, bfx, fb, h_all,
          hs_r, hbe_r, cp_r, hs_w, hbe_w, cp_w, out, s, L, T16, (d == 0) ? 1 : 0, lns);
    }
  }
}

// Round 20
// 690.343 us; speedup vs baseline: 1.4691x; 1.1644x over previous
//
#include <hip/hip_runtime.h>

// ---------------------------------------------------------------------------
// Child-Sum TreeLSTM, complete binary tree, level-wise bottom-up, bf16 MFMA.
// Round 20 = R13 body (VGPR 60, no spill) + TILE-MAJOR A-data:
//   R19 proved occupancy is not the lever (leaf 16->32 waves/CU: 0 gain).
//   All pipes <35% busy; effective in-flight ~13 lines/CU -> the per-CU
//   address path serializes our 16-line gathers (16 rows x 512B stride per
//   A-load). Fix: xb/hs/hbe stored in MFMA fragment order per 16-row tile
//   [tile][kc8][row16][kg4][e8] -> each A-frag load = 1KB CONTIGUOUS.
//   Writers (conv_x, child epilogue) scatter a bit more (2B/16B stores) --
//   cheap vs. the read win. Body math & launch identical to R13/R19.
// Level bases padded: P(d) = d<4 ? 16*d : 48 + 2^d  (rows), so tile-major
// regions of tiny levels don't collide.
// Tripwires (lvl16): FETCH ~8.6e4 KB, WRITE ~1.5e5 KB, VGPR ~60.
//
// mfma_f32_16x16x32_bf16: A lane: row=l&15, k=(l>>4)*8+e  (16B/lane)
//                         B lane: col=l&15, k=(l>>4)*8+e = W[col][k]
//                         D: col=l&15, row=(l>>4)*4+r, r=0..3
// ---------------------------------------------------------------------------

typedef __attribute__((ext_vector_type(8))) short bf16x8;
typedef __attribute__((ext_vector_type(8))) unsigned short us8;
typedef __attribute__((ext_vector_type(4))) float f32x4;
typedef __attribute__((ext_vector_type(4))) float f4;

#define MFMA16(A, B, C) __builtin_amdgcn_mfma_f32_16x16x32_bf16(A, B, C, 0, 0, 0)

__device__ __forceinline__ unsigned short f2b(float f) {
  unsigned int u = __builtin_bit_cast(unsigned int, f);
  u = u + 0x7FFFu + ((u >> 16) & 1u);   // RNE
  return (unsigned short)(u >> 16);
}
__device__ __forceinline__ float bf2f(unsigned short u) {
  unsigned int v = (unsigned int)u << 16;
  return __builtin_bit_cast(float, v);
}
__device__ __forceinline__ us8 pack8(f4 a, f4 b) {
  us8 r;
  r[0] = f2b(a[0]); r[1] = f2b(a[1]); r[2] = f2b(a[2]); r[3] = f2b(a[3]);
  r[4] = f2b(b[0]); r[5] = f2b(b[1]); r[6] = f2b(b[2]); r[7] = f2b(b[3]);
  return r;
}
__device__ __forceinline__ float sigm(float x) { return 1.0f / (1.0f + __expf(-x)); }
__device__ __forceinline__ float tanh_f(float x) { return 2.0f / (1.0f + __expf(-2.0f * x)) - 1.0f; }

__global__ void pack_w(const float* __restrict__ a,  // Wioux 768x256
                       const float* __restrict__ b,  // Wiouh 768x256
                       const float* __restrict__ c,  // Wfx   256x256
                       const float* __restrict__ d,  // Wfh   256x256
                       unsigned short* __restrict__ out) {
  int i = blockIdx.x * blockDim.x + threadIdx.x;  // 0 .. 524287
  const int A = 768 * 256;
  const int B = A + 768 * 256;
  const int C = B + 256 * 256;
  float v;
  if (i < A)      v = a[i];
  else if (i < B) v = b[i - A];
  else if (i < C) v = c[i - B];
  else            v = d[i - C];
  out[i] = f2b(v);
}

// convert ALL node x rows to bf16, TILE-MAJOR per level:
// level-local row r, col = kc*32 + kg*8 + e ->
//   off = P(d)*256 + ((r>>4)*8 + kc)*512 + (r&15)*32 + kg*8 + e
__global__ void conv_x(const float* __restrict__ x, unsigned short* __restrict__ xb, int n32) {
  int i = blockIdx.x * blockDim.x + threadIdx.x;   // node*32 + g
  if (i >= n32) return;
  const int n = i >> 5, g = i & 31;                // g*8 = col base
  f4 a = __builtin_nontemporal_load((const f4*)(x + (size_t)n * 256 + g * 8));
  f4 b = __builtin_nontemporal_load((const f4*)(x + (size_t)n * 256 + g * 8 + 4));
  const int d = 31 - __clz(n + 1);
  const int r = n - ((1 << d) - 1);
  const size_t base = (size_t)((d < 4) ? d * 16 : 48 + (1 << d)) * 256;
  const size_t off = base + ((size_t)((r >> 4) * 8 + (g >> 2)) * 16 + (r & 15)) * 32
                     + (g & 3) * 8;
  __builtin_nontemporal_store(pack8(a, b), (us8*)(xb + off));
}

// LDS planes: 0 Wx_i, 1 Wx_o, 2 Wx_u, 3 Wh_i, 4 Wh_o, 5 Wh_u, 6 Wfx, 7 Wfh
// per plane: [kc8][kg4][col16][e8] -> a wave's b128 read is 1KB contiguous.
template<int LEAF>
__global__ __launch_bounds__(512) __attribute__((amdgpu_waves_per_eu(3, 4)))
void level_k(
    const unsigned short* __restrict__ xlv,    // level-base of tile-major xb
    const unsigned short* __restrict__ wb,     // packed bf16 weights
    const float* __restrict__ bioux,
    const float* __restrict__ bfx,
    const float* __restrict__ fb,
    float* __restrict__ h_all,                 // d_out + 512 (row-major f32)
    const unsigned short* __restrict__ hs_r,   // tile-major, this-level-local
    const unsigned short* __restrict__ hbe_r,  // tile-major
    const unsigned int* __restrict__ cp_r,     // row-major packed (ce|co<<16)
    unsigned short* __restrict__ hs_w,         // tile-major, parent-level-local
    unsigned short* __restrict__ hbe_w,
    unsigned int* __restrict__ cp_w,
    float* __restrict__ out0,
    int s, int L, int T16, int root, int lns)  // lns: log2(stripe count)
{
  extern __shared__ unsigned short W[];

  const int tid    = threadIdx.x;
  const int NS     = 1 << lns;
  const int cg     = blockIdx.x >> lns;       // column group (16 cols)
  const int stripe = blockIdx.x & (NS - 1);

  // ---- stage weights for this cg into LDS (once) ----
  const int NP = LEAF ? 3 : 8;
  #pragma unroll 1
  for (int c = tid; c < NP * 512; c += 512) {
    const int p   = c >> 9;
    const int q   = c & 511;
    const int kc  = q >> 6;
    const int kg  = (q >> 4) & 3;
    const int col = q & 15;
    const int po = (p < 3) ? p * 65536
                 : (p < 6) ? 196608 + (p - 3) * 65536
                 : (p == 6) ? 393216 : 458752;
    us8 v = *(const us8*)(wb + po + (size_t)(cg * 16 + col) * 256 + kc * 32 + kg * 8);
    *(us8*)(W + p * 4096 + ((kc * 4 + kg) * 16 + col) * 8) = v;
  }
  __syncthreads();   // only barrier; waves free-run after

  const int lane = tid & 63;
  const int wv   = tid >> 6;          // 0..7
  const int lm   = lane & 15;
  const int kgl  = lane >> 4;         // 0..3
  const int colc = cg * 16 + lm;

  const unsigned short* LW = W + kgl * 128 + lm * 8;  // + p*4096 + kc*512

  // tile-major write coords for this lane's output column
  const int kcw = colc >> 5;
  const int kgw = (colc >> 3) & 3;
  const int ew  = colc & 7;

  const float bi_ = bioux[colc];
  const float bo_ = bioux[256 + colc];
  const float bu_ = bioux[512 + colc];
  const float bf_ = LEAF ? 0.f : (bfx[colc] + fb[colc]);

  const int Tper = (T16 + NS - 1) >> lns;
  const int t0   = stripe * Tper;
  const int tE   = (t0 + Tper < T16) ? (t0 + Tper) : T16;

  for (int t = t0 + wv; t < tE; t += 8) {
    const int tb16  = t * 16;
    const int drow0 = tb16 + kgl * 4;
    // tile-major A base: tile t, lane (lm, kgl); step per kc = 512 elems (1KB)
    const size_t abase = (size_t)t * 4096 + lm * 32 + kgl * 8;
    const unsigned short* xr = xlv + abase;
    const f32x4 z4 = {0.f, 0.f, 0.f, 0.f};

    if (!LEAF) {
      const unsigned short* hbr = hbe_r + abase;
      const unsigned short* hsr = hs_r  + abase;

      unsigned int cpv[4];
      #pragma unroll
      for (int r = 0; r < 4; ++r)
        cpv[r] = cp_r[(size_t)(drow0 + r) * 256 + colc];

      // ---- merged K-sweep: all 6 acc planes, each A-frag loaded once ----
      f32x4 xf = z4, f1h = z4, ai = z4, ao = z4, au = z4, fs = z4;
      #pragma unroll 2
      for (int kc = 0; kc < 8; ++kc) {
        bf16x8 ax = *(const bf16x8*)(xr  + kc * 512);
        bf16x8 a1 = *(const bf16x8*)(hbr + kc * 512);
        bf16x8 ah = *(const bf16x8*)(hsr + kc * 512);
        bf16x8 b6 = *(const bf16x8*)(LW + 6 * 4096 + kc * 512);
        bf16x8 b0 = *(const bf16x8*)(LW + 0 * 4096 + kc * 512);
        bf16x8 b1 = *(const bf16x8*)(LW + 1 * 4096 + kc * 512);
        bf16x8 b2 = *(const bf16x8*)(LW + 2 * 4096 + kc * 512);
        bf16x8 b7 = *(const bf16x8*)(LW + 7 * 4096 + kc * 512);
        bf16x8 b3 = *(const bf16x8*)(LW + 3 * 4096 + kc * 512);
        bf16x8 b4 = *(const bf16x8*)(LW + 4 * 4096 + kc * 512);
        bf16x8 b5 = *(const bf16x8*)(LW + 5 * 4096 + kc * 512);
        xf  = MFMA16(ax, b6, xf);
        ai  = MFMA16(ax, b0, ai);
        ao  = MFMA16(ax, b1, ao);
        au  = MFMA16(ax, b2, au);
        f1h = MFMA16(a1, b7, f1h);
        ai  = MFMA16(ah, b3, ai);
        ao  = MFMA16(ah, b4, ao);
        au  = MFMA16(ah, b5, au);
        fs  = MFMA16(ah, b7, fs);
      }

      // ---- epilogue ----
      float hv4[4], cv4[4];
      #pragma unroll
      for (int r = 0; r < 4; ++r) {
        const float i_ = sigm(ai[r] + bi_);
        const float u_ = tanh_f(au[r] + bu_);
        const float o_ = sigm(ao[r] + bo_);
        const float f1 = sigm(xf[r] + f1h[r] + bf_);
        const float f2 = sigm(xf[r] + fs[r] - f1h[r] + bf_);  // h2@W = hs@W - h1@W
        const float c1 = bf2f((unsigned short)(cpv[r] & 0xffffu));
        const float c2 = bf2f((unsigned short)(cpv[r] >> 16));
        const float c_ = i_ * u_ + f1 * c1 + f2 * c2;
        const float h_ = o_ * tanh_f(c_);
        cv4[r] = c_; hv4[r] = h_;
        const int j = drow0 + r;
        if (j < L)
          __builtin_nontemporal_store(h_, h_all + (size_t)(s + j) * 256 + colc);
      }
      if (root) {
        if (drow0 == 0) { out0[colc] = hv4[0]; out0[256 + colc] = cv4[0]; }
      } else {
        #pragma unroll
        for (int rp = 0; rp < 2; ++rp) {
          const int j0 = drow0 + rp * 2;
          if (j0 + 1 < L) {
            const int pp = j0 >> 1;
            const size_t toff = ((size_t)((pp >> 4) * 8 + kcw) * 16 + (pp & 15)) * 32
                                + kgw * 8 + ew;
            hs_w [toff] = f2b(hv4[rp*2] + hv4[rp*2+1]);
            hbe_w[toff] = f2b(hv4[rp*2]);
            cp_w [(size_t)pp * 256 + colc] =
                (unsigned int)f2b(cv4[rp*2]) | ((unsigned int)f2b(cv4[rp*2+1]) << 16);
          }
        }
      }
    } else {
      // ---- leaf: i,o,u from x only ----
      f32x4 ai = z4, ao = z4, au = z4;
      #pragma unroll 4
      for (int kc = 0; kc < 8; ++kc) {
        bf16x8 ax = *(const bf16x8*)(xr + kc * 512);
        bf16x8 b0 = *(const bf16x8*)(LW + 0 * 4096 + kc * 512);
        bf16x8 b1 = *(const bf16x8*)(LW + 1 * 4096 + kc * 512);
        bf16x8 b2 = *(const bf16x8*)(LW + 2 * 4096 + kc * 512);
        ai = MFMA16(ax, b0, ai);
        ao = MFMA16(ax, b1, ao);
        au = MFMA16(ax, b2, au);
      }
      float hv4[4], cv4[4];
      #pragma unroll
      for (int r = 0; r < 4; ++r) {
        const float i_ = sigm(ai[r] + bi_);
        const float u_ = tanh_f(au[r] + bu_);
        const float o_ = sigm(ao[r] + bo_);
        const float c_ = i_ * u_;
        const float h_ = o_ * tanh_f(c_);
        cv4[r] = c_; hv4[r] = h_;
        __builtin_nontemporal_store(h_, h_all + (size_t)(s + drow0 + r) * 256 + colc);
      }
      #pragma unroll
      for (int rp = 0; rp < 2; ++rp) {
        const int pp = (drow0 + rp * 2) >> 1;
        const size_t toff = ((size_t)((pp >> 4) * 8 + kcw) * 16 + (pp & 15)) * 32
                            + kgw * 8 + ew;
        hs_w [toff] = f2b(hv4[rp*2] + hv4[rp*2+1]);
        hbe_w[toff] = f2b(hv4[rp*2]);
        cp_w [(size_t)pp * 256 + colc] =
            (unsigned int)f2b(cv4[rp*2]) | ((unsigned int)f2b(cv4[rp*2+1]) << 16);
      }
    }
  }
}

extern "C" void kernel_launch(void* const* d_in, const int* in_sizes, int n_in,
                              void* d_out, int out_size, void* d_ws, size_t ws_size,
                              hipStream_t stream) {
  const float* inputs = (const float*)d_in[0];
  const float* Wioux  = (const float*)d_in[1];
  const float* bioux  = (const float*)d_in[2];
  const float* Wiouh  = (const float*)d_in[3];
  const float* Wfx    = (const float*)d_in[4];
  const float* bfx    = (const float*)d_in[5];
  const float* Wfh    = (const float*)d_in[6];
  const float* fb     = (const float*)d_in[7];

  const int N = in_sizes[0] / 256;       // 262143
  int depth = 0;
  while (((1 << depth) - 1) < N) ++depth;  // 18

  float* out   = (float*)d_out;
  float* h_all = out + 512;

  static bool attr_done = false;
  if (!attr_done) {
    hipFuncSetAttribute((const void*)level_k<0>,
                        hipFuncAttributeMaxDynamicSharedMemorySize, 8 * 8192);
    hipFuncSetAttribute((const void*)level_k<1>,
                        hipFuncAttributeMaxDynamicSharedMemorySize, 3 * 8192);
    attr_done = true;
  }

  // ws carve: parity-0 buffers (up to 65536 rows), parity-1 (32768),
  // xb tile-major (N + 49 padded rows), wb
  char* p = (char*)d_ws;
  unsigned short* hs0  = (unsigned short*)p; p += (size_t)65536 * 256 * 2;
  unsigned short* hbe0 = (unsigned short*)p; p += (size_t)65536 * 256 * 2;
  unsigned int*   cp0  = (unsigned int*)p;   p += (size_t)65536 * 256 * 4;
  unsigned short* hs1  = (unsigned short*)p; p += (size_t)32768 * 256 * 2;
  unsigned short* hbe1 = (unsigned short*)p; p += (size_t)32768 * 256 * 2;
  unsigned int*   cp1  = (unsigned int*)p;   p += (size_t)32768 * 256 * 4;
  unsigned short* xb   = (unsigned short*)p; p += (size_t)(N + 64) * 256 * 2;
  unsigned short* wb   = (unsigned short*)p;

  pack_w<<<2048, 256, 0, stream>>>(Wioux, Wiouh, Wfx, Wfh, wb);
  {
    const int n32 = N * 32;
    conv_x<<<(n32 + 255) / 256, 256, 0, stream>>>(inputs, xb, n32);
  }

  for (int d = depth - 1; d >= 0; --d) {
    const int L = 1 << d;
    const int s = L - 1;
    const int T16 = (L + 15) / 16;
    const size_t Pb = (size_t)((d < 4) ? d * 16 : 48 + (1 << d)) * 256;
    // interior stripes: aim Tper ~ 8-16, cap NS=32
    int lg = 0; while ((1 << (lg + 1)) <= T16) ++lg;   // floor(log2 T16)
    int lns = lg - 3; if (lns < 0) lns = 0; if (lns > 5) lns = 5;
    const int rp_ = d & 1, wp_ = (d - 1) & 1;
    const unsigned short* hs_r  = rp_ ? hs1 : hs0;
    const unsigned short* hbe_r = rp_ ? hbe1 : hbe0;
    const unsigned int*   cp_r  = rp_ ? cp1 : cp0;
    unsigned short* hs_w  = wp_ ? hs1 : hs0;
    unsigned short* hbe_w = wp_ ? hbe1 : hbe0;
    unsigned int*   cp_w  = wp_ ? cp1 : cp0;
    if (d == depth - 1) {
      // leaf: 24KB LDS -> 4 blocks/CU; grid 1024 (lns=6)
      level_k<1><<<16 * 64, 512, 3 * 8192, stream>>>(
          xb + Pb, wb, bioux, bfx, fb, h_all,
          hs_r, hbe_r, cp_r, hs_w, hbe_w, cp_w, out, s, L, T16, 0, 6);
    } else {
      // interior: 64KB LDS -> 2 blocks/CU; grid = 16 << lns (512 at big levels)
      level_k<0><<<16 << lns, 512, 8 * 8192, stream>>>(
          xb + Pb, wb, bioux, bfx, fb, h_all,
          hs_r, hbe_r, cp_r, hs_w, hbe_w, cp_w, out, s, L, T16, (d == 0) ? 1 : 0, lns);
    }
  }
}

// Round 21
// 681.521 us; speedup vs baseline: 1.4881x; 1.0129x over previous
//
#include <hip/hip_runtime.h>

// ---------------------------------------------------------------------------
// Child-Sum TreeLSTM, complete binary tree, level-wise bottom-up, bf16 MFMA.
// Round 21 = R20 (tile-major A: lvl16 233->185us) + two latency fixes:
//  (1) interior K-sweep unroll 4 (was 2): ~12 loads in flight per wave
//  (2) cp (packed child-c) TILE-MAJOR [tile][cg16][r4][kgl4][lm16]:
//      reader load = 1 contiguous 256B transaction (lane = kgl*16+lm);
//      writer scatters 64B chunks (stores don't stall).
// Everything else byte-identical to R20 (VGPR 56, no spill).
// Tripwires (lvl16): FETCH ~8.6e4 KB, WRITE ~1.5e5 KB; inflation = spill.
//
// mfma_f32_16x16x32_bf16: A lane: row=l&15, k=(l>>4)*8+e  (16B/lane)
//                         B lane: col=l&15, k=(l>>4)*8+e = W[col][k]
//                         D: col=l&15, row=(l>>4)*4+r, r=0..3
// ---------------------------------------------------------------------------

typedef __attribute__((ext_vector_type(8))) short bf16x8;
typedef __attribute__((ext_vector_type(8))) unsigned short us8;
typedef __attribute__((ext_vector_type(4))) float f32x4;
typedef __attribute__((ext_vector_type(4))) float f4;

#define MFMA16(A, B, C) __builtin_amdgcn_mfma_f32_16x16x32_bf16(A, B, C, 0, 0, 0)

__device__ __forceinline__ unsigned short f2b(float f) {
  unsigned int u = __builtin_bit_cast(unsigned int, f);
  u = u + 0x7FFFu + ((u >> 16) & 1u);   // RNE
  return (unsigned short)(u >> 16);
}
__device__ __forceinline__ float bf2f(unsigned short u) {
  unsigned int v = (unsigned int)u << 16;
  return __builtin_bit_cast(float, v);
}
__device__ __forceinline__ us8 pack8(f4 a, f4 b) {
  us8 r;
  r[0] = f2b(a[0]); r[1] = f2b(a[1]); r[2] = f2b(a[2]); r[3] = f2b(a[3]);
  r[4] = f2b(b[0]); r[5] = f2b(b[1]); r[6] = f2b(b[2]); r[7] = f2b(b[3]);
  return r;
}
__device__ __forceinline__ float sigm(float x) { return 1.0f / (1.0f + __expf(-x)); }
__device__ __forceinline__ float tanh_f(float x) { return 2.0f / (1.0f + __expf(-2.0f * x)) - 1.0f; }

__global__ void pack_w(const float* __restrict__ a,  // Wioux 768x256
                       const float* __restrict__ b,  // Wiouh 768x256
                       const float* __restrict__ c,  // Wfx   256x256
                       const float* __restrict__ d,  // Wfh   256x256
                       unsigned short* __restrict__ out) {
  int i = blockIdx.x * blockDim.x + threadIdx.x;  // 0 .. 524287
  const int A = 768 * 256;
  const int B = A + 768 * 256;
  const int C = B + 256 * 256;
  float v;
  if (i < A)      v = a[i];
  else if (i < B) v = b[i - A];
  else if (i < C) v = c[i - B];
  else            v = d[i - C];
  out[i] = f2b(v);
}

// convert ALL node x rows to bf16, TILE-MAJOR per level:
// level-local row r, col = kc*32 + kg*8 + e ->
//   off = P(d)*256 + ((r>>4)*8 + kc)*512 + (r&15)*32 + kg*8 + e
__global__ void conv_x(const float* __restrict__ x, unsigned short* __restrict__ xb, int n32) {
  int i = blockIdx.x * blockDim.x + threadIdx.x;   // node*32 + g
  if (i >= n32) return;
  const int n = i >> 5, g = i & 31;                // g*8 = col base
  f4 a = __builtin_nontemporal_load((const f4*)(x + (size_t)n * 256 + g * 8));
  f4 b = __builtin_nontemporal_load((const f4*)(x + (size_t)n * 256 + g * 8 + 4));
  const int d = 31 - __clz(n + 1);
  const int r = n - ((1 << d) - 1);
  const size_t base = (size_t)((d < 4) ? d * 16 : 48 + (1 << d)) * 256;
  const size_t off = base + ((size_t)((r >> 4) * 8 + (g >> 2)) * 16 + (r & 15)) * 32
                     + (g & 3) * 8;
  __builtin_nontemporal_store(pack8(a, b), (us8*)(xb + off));
}

// LDS planes: 0 Wx_i, 1 Wx_o, 2 Wx_u, 3 Wh_i, 4 Wh_o, 5 Wh_u, 6 Wfx, 7 Wfh
// per plane: [kc8][kg4][col16][e8] -> a wave's b128 read is 1KB contiguous.
template<int LEAF>
__global__ __launch_bounds__(512) __attribute__((amdgpu_waves_per_eu(3, 4)))
void level_k(
    const unsigned short* __restrict__ xlv,    // level-base of tile-major xb
    const unsigned short* __restrict__ wb,     // packed bf16 weights
    const float* __restrict__ bioux,
    const float* __restrict__ bfx,
    const float* __restrict__ fb,
    float* __restrict__ h_all,                 // d_out + 512 (row-major f32)
    const unsigned short* __restrict__ hs_r,   // tile-major, this-level-local
    const unsigned short* __restrict__ hbe_r,  // tile-major
    const unsigned int* __restrict__ cp_r,     // tile-major [t][cg][r][kgl][lm]
    unsigned short* __restrict__ hs_w,         // tile-major, parent-level-local
    unsigned short* __restrict__ hbe_w,
    unsigned int* __restrict__ cp_w,
    float* __restrict__ out0,
    int s, int L, int T16, int root, int lns)  // lns: log2(stripe count)
{
  extern __shared__ unsigned short W[];

  const int tid    = threadIdx.x;
  const int NS     = 1 << lns;
  const int cg     = blockIdx.x >> lns;       // column group (16 cols)
  const int stripe = blockIdx.x & (NS - 1);

  // ---- stage weights for this cg into LDS (once) ----
  const int NP = LEAF ? 3 : 8;
  #pragma unroll 1
  for (int c = tid; c < NP * 512; c += 512) {
    const int p   = c >> 9;
    const int q   = c & 511;
    const int kc  = q >> 6;
    const int kg  = (q >> 4) & 3;
    const int col = q & 15;
    const int po = (p < 3) ? p * 65536
                 : (p < 6) ? 196608 + (p - 3) * 65536
                 : (p == 6) ? 393216 : 458752;
    us8 v = *(const us8*)(wb + po + (size_t)(cg * 16 + col) * 256 + kc * 32 + kg * 8);
    *(us8*)(W + p * 4096 + ((kc * 4 + kg) * 16 + col) * 8) = v;
  }
  __syncthreads();   // only barrier; waves free-run after

  const int lane = tid & 63;
  const int wv   = tid >> 6;          // 0..7
  const int lm   = lane & 15;
  const int kgl  = lane >> 4;         // 0..3
  const int colc = cg * 16 + lm;

  const unsigned short* LW = W + kgl * 128 + lm * 8;  // + p*4096 + kc*512

  // tile-major write coords for this lane's output column
  const int kcw = colc >> 5;
  const int kgw = (colc >> 3) & 3;
  const int ew  = colc & 7;

  const float bi_ = bioux[colc];
  const float bo_ = bioux[256 + colc];
  const float bu_ = bioux[512 + colc];
  const float bf_ = LEAF ? 0.f : (bfx[colc] + fb[colc]);

  const int Tper = (T16 + NS - 1) >> lns;
  const int t0   = stripe * Tper;
  const int tE   = (t0 + Tper < T16) ? (t0 + Tper) : T16;

  for (int t = t0 + wv; t < tE; t += 8) {
    const int tb16  = t * 16;
    const int drow0 = tb16 + kgl * 4;
    // tile-major A base: tile t, lane (lm, kgl); step per kc = 512 elems (1KB)
    const size_t abase = (size_t)t * 4096 + lm * 32 + kgl * 8;
    const unsigned short* xr = xlv + abase;
    const f32x4 z4 = {0.f, 0.f, 0.f, 0.f};

    if (!LEAF) {
      const unsigned short* hbr = hbe_r + abase;
      const unsigned short* hsr = hs_r  + abase;

      // cp tile-major read: one contiguous 256B load per r (lane = kgl*16+lm)
      unsigned int cpv[4];
      #pragma unroll
      for (int r = 0; r < 4; ++r)
        cpv[r] = cp_r[(size_t)t * 4096 + cg * 256 + r * 64 + kgl * 16 + lm];

      // ---- merged K-sweep: all 6 acc planes, each A-frag loaded once ----
      f32x4 xf = z4, f1h = z4, ai = z4, ao = z4, au = z4, fs = z4;
      #pragma unroll 4
      for (int kc = 0; kc < 8; ++kc) {
        bf16x8 ax = *(const bf16x8*)(xr  + kc * 512);
        bf16x8 a1 = *(const bf16x8*)(hbr + kc * 512);
        bf16x8 ah = *(const bf16x8*)(hsr + kc * 512);
        bf16x8 b6 = *(const bf16x8*)(LW + 6 * 4096 + kc * 512);
        bf16x8 b0 = *(const bf16x8*)(LW + 0 * 4096 + kc * 512);
        bf16x8 b1 = *(const bf16x8*)(LW + 1 * 4096 + kc * 512);
        bf16x8 b2 = *(const bf16x8*)(LW + 2 * 4096 + kc * 512);
        bf16x8 b7 = *(const bf16x8*)(LW + 7 * 4096 + kc * 512);
        bf16x8 b3 = *(const bf16x8*)(LW + 3 * 4096 + kc * 512);
        bf16x8 b4 = *(const bf16x8*)(LW + 4 * 4096 + kc * 512);
        bf16x8 b5 = *(const bf16x8*)(LW + 5 * 4096 + kc * 512);
        xf  = MFMA16(ax, b6, xf);
        ai  = MFMA16(ax, b0, ai);
        ao  = MFMA16(ax, b1, ao);
        au  = MFMA16(ax, b2, au);
        f1h = MFMA16(a1, b7, f1h);
        ai  = MFMA16(ah, b3, ai);
        ao  = MFMA16(ah, b4, ao);
        au  = MFMA16(ah, b5, au);
        fs  = MFMA16(ah, b7, fs);
      }

      // ---- epilogue ----
      float hv4[4], cv4[4];
      #pragma unroll
      for (int r = 0; r < 4; ++r) {
        const float i_ = sigm(ai[r] + bi_);
        const float u_ = tanh_f(au[r] + bu_);
        const float o_ = sigm(ao[r] + bo_);
        const float f1 = sigm(xf[r] + f1h[r] + bf_);
        const float f2 = sigm(xf[r] + fs[r] - f1h[r] + bf_);  // h2@W = hs@W - h1@W
        const float c1 = bf2f((unsigned short)(cpv[r] & 0xffffu));
        const float c2 = bf2f((unsigned short)(cpv[r] >> 16));
        const float c_ = i_ * u_ + f1 * c1 + f2 * c2;
        const float h_ = o_ * tanh_f(c_);
        cv4[r] = c_; hv4[r] = h_;
        const int j = drow0 + r;
        if (j < L)
          __builtin_nontemporal_store(h_, h_all + (size_t)(s + j) * 256 + colc);
      }
      if (root) {
        if (drow0 == 0) { out0[colc] = hv4[0]; out0[256 + colc] = cv4[0]; }
      } else {
        #pragma unroll
        for (int rp = 0; rp < 2; ++rp) {
          const int j0 = drow0 + rp * 2;
          if (j0 + 1 < L) {
            const int pp = j0 >> 1;
            const int q  = pp & 15;
            const size_t toff = ((size_t)((pp >> 4) * 8 + kcw) * 16 + q) * 32
                                + kgw * 8 + ew;
            hs_w [toff] = f2b(hv4[rp*2] + hv4[rp*2+1]);
            hbe_w[toff] = f2b(hv4[rp*2]);
            cp_w [(size_t)(pp >> 4) * 4096 + cg * 256 + (q & 3) * 64
                  + (q >> 2) * 16 + lm] =
                (unsigned int)f2b(cv4[rp*2]) | ((unsigned int)f2b(cv4[rp*2+1]) << 16);
          }
        }
      }
    } else {
      // ---- leaf: i,o,u from x only ----
      f32x4 ai = z4, ao = z4, au = z4;
      #pragma unroll 4
      for (int kc = 0; kc < 8; ++kc) {
        bf16x8 ax = *(const bf16x8*)(xr + kc * 512);
        bf16x8 b0 = *(const bf16x8*)(LW + 0 * 4096 + kc * 512);
        bf16x8 b1 = *(const bf16x8*)(LW + 1 * 4096 + kc * 512);
        bf16x8 b2 = *(const bf16x8*)(LW + 2 * 4096 + kc * 512);
        ai = MFMA16(ax, b0, ai);
        ao = MFMA16(ax, b1, ao);
        au = MFMA16(ax, b2, au);
      }
      float hv4[4], cv4[4];
      #pragma unroll
      for (int r = 0; r < 4; ++r) {
        const float i_ = sigm(ai[r] + bi_);
        const float u_ = tanh_f(au[r] + bu_);
        const float o_ = sigm(ao[r] + bo_);
        const float c_ = i_ * u_;
        const float h_ = o_ * tanh_f(c_);
        cv4[r] = c_; hv4[r] = h_;
        __builtin_nontemporal_store(h_, h_all + (size_t)(s + drow0 + r) * 256 + colc);
      }
      #pragma unroll
      for (int rp = 0; rp < 2; ++rp) {
        const int pp = (drow0 + rp * 2) >> 1;
        const int q  = pp & 15;
        const size_t toff = ((size_t)((pp >> 4) * 8 + kcw) * 16 + q) * 32
                            + kgw * 8 + ew;
        hs_w [toff] = f2b(hv4[rp*2] + hv4[rp*2+1]);
        hbe_w[toff] = f2b(hv4[rp*2]);
        cp_w [(size_t)(pp >> 4) * 4096 + cg * 256 + (q & 3) * 64
              + (q >> 2) * 16 + lm] =
            (unsigned int)f2b(cv4[rp*2]) | ((unsigned int)f2b(cv4[rp*2+1]) << 16);
      }
    }
  }
}

extern "C" void kernel_launch(void* const* d_in, const int* in_sizes, int n_in,
                              void* d_out, int out_size, void* d_ws, size_t ws_size,
                              hipStream_t stream) {
  const float* inputs = (const float*)d_in[0];
  const float* Wioux  = (const float*)d_in[1];
  const float* bioux  = (const float*)d_in[2];
  const float* Wiouh  = (const float*)d_in[3];
  const float* Wfx    = (const float*)d_in[4];
  const float* bfx    = (const float*)d_in[5];
  const float* Wfh    = (const float*)d_in[6];
  const float* fb     = (const float*)d_in[7];

  const int N = in_sizes[0] / 256;       // 262143
  int depth = 0;
  while (((1 << depth) - 1) < N) ++depth;  // 18

  float* out   = (float*)d_out;
  float* h_all = out + 512;

  static bool attr_done = false;
  if (!attr_done) {
    hipFuncSetAttribute((const void*)level_k<0>,
                        hipFuncAttributeMaxDynamicSharedMemorySize, 8 * 8192);
    hipFuncSetAttribute((const void*)level_k<1>,
                        hipFuncAttributeMaxDynamicSharedMemorySize, 3 * 8192);
    attr_done = true;
  }

  // ws carve: parity-0 buffers (up to 65536 rows), parity-1 (32768),
  // xb tile-major (N + pad), wb
  char* p = (char*)d_ws;
  unsigned short* hs0  = (unsigned short*)p; p += (size_t)65536 * 256 * 2;
  unsigned short* hbe0 = (unsigned short*)p; p += (size_t)65536 * 256 * 2;
  unsigned int*   cp0  = (unsigned int*)p;   p += (size_t)65536 * 256 * 4;
  unsigned short* hs1  = (unsigned short*)p; p += (size_t)32768 * 256 * 2;
  unsigned short* hbe1 = (unsigned short*)p; p += (size_t)32768 * 256 * 2;
  unsigned int*   cp1  = (unsigned int*)p;   p += (size_t)32768 * 256 * 4;
  unsigned short* xb   = (unsigned short*)p; p += (size_t)(N + 64) * 256 * 2;
  unsigned short* wb   = (unsigned short*)p;

  pack_w<<<2048, 256, 0, stream>>>(Wioux, Wiouh, Wfx, Wfh, wb);
  {
    const int n32 = N * 32;
    conv_x<<<(n32 + 255) / 256, 256, 0, stream>>>(inputs, xb, n32);
  }

  for (int d = depth - 1; d >= 0; --d) {
    const int L = 1 << d;
    const int s = L - 1;
    const int T16 = (L + 15) / 16;
    const size_t Pb = (size_t)((d < 4) ? d * 16 : 48 + (1 << d)) * 256;
    // interior stripes: aim Tper ~ 8-16, cap NS=32
    int lg = 0; while ((1 << (lg + 1)) <= T16) ++lg;   // floor(log2 T16)
    int lns = lg - 3; if (lns < 0) lns = 0; if (lns > 5) lns = 5;
    const int rp_ = d & 1, wp_ = (d - 1) & 1;
    const unsigned short* hs_r  = rp_ ? hs1 : hs0;
    const unsigned short* hbe_r = rp_ ? hbe1 : hbe0;
    const unsigned int*   cp_r  = rp_ ? cp1 : cp0;
    unsigned short* hs_w  = wp_ ? hs1 : hs0;
    unsigned short* hbe_w = wp_ ? hbe1 : hbe0;
    unsigned int*   cp_w  = wp_ ? cp1 : cp0;
    if (d == depth - 1) {
      // leaf: 24KB LDS -> 4 blocks/CU; grid 1024 (lns=6)
      level_k<1><<<16 * 64, 512, 3 * 8192, stream>>>(
          xb + Pb, wb, bioux, bfx, fb, h_all,
          hs_r, hbe_r, cp_r, hs_w, hbe_w, cp_w, out, s, L, T16, 0, 6);
    } else {
      // interior: 64KB LDS -> 2 blocks/CU; grid = 16 << lns (512 at big levels)
      level_k<0><<<16 << lns, 512, 8 * 8192, stream>>>(
          xb + Pb, wb, bioux, bfx, fb, h_all,
          hs_r, hbe_r, cp_r, hs_w, hbe_w, cp_w, out, s, L, T16, (d == 0) ? 1 : 0, lns);
    }
  }
}